// Round 9
// baseline (233.760 us; speedup 1.0000x reference)
//
#include <hip/hip_runtime.h>

using u16 = unsigned short;
using u32 = unsigned int;
typedef __attribute__((ext_vector_type(8))) short bf16x8;
typedef __attribute__((ext_vector_type(4))) float f32x4;

// ---------- posit(8,1) round-to-nearest (float core, verified bit-exact on HW) ----------
// PITFALL (R19): do NOT use v_pk_fma_f32 / packed f32 math anywhere feeding the posit quantizer.
// Packed FMA flushes denormal results (FTZ); scalar v_fma_f32 preserves them. Positive denormal
// conv sums map to posit minpos 2^-12 in the reference — FTZ turns them into 0 and the 2.4e-4
// perturbation amplifies to ~5e-3 at the output (failed absmax). Scalar fmaf chains only.
__device__ __forceinline__ float posit_q(float x) {
    float a = __builtin_fabsf(x);
    u32 u = __float_as_uint(a);
    int logx = (int)(u >> 23) - 127;
    logx = logx < -60 ? -60 : (logx > 60 ? 60 : logx);
    float frac = __uint_as_float((u & 0x007fffffu) | 0x3f800000u);  // [1,2)
    int k = logx >> 1;                            // floor(logx/2), es=1
    int rl = (k >= 0) ? (k + 2) : (1 - k);        // regime length
    int fb = 6 - rl; fb = fb < 0 ? 0 : fb;        // fraction bits, <=4
    float step = (float)(1 << fb);
    float q = rintf(frac * step) * __uint_as_float((u32)(127 + logx - fb) << 23);
    q = fminf(fmaxf(q, 0x1p-12f), 0x1p12f);
    return (a > 0.0f) ? copysignf(q, x) : 0.0f;
}

__device__ __forceinline__ float b2f(u16 v) { return __uint_as_float((u32)v << 16); }
__device__ __forceinline__ u16 f2b(float f) { return (u16)(__float_as_uint(f) >> 16); }  // exact for posit values

// ---------- Dekker-LUT posit quantizer (exact RNE onto the posit grid; verified R8) ----------
__device__ __forceinline__ void lut_init(int tid, float* lut) {
    if (tid < 256) {
        int e = tid - 127;
        float m = 0.f;
        if (e >= -12 && e <= 12) {
            int k = e >> 1;
            int rl = max(k + 2, 1 - k);
            int fb = max(6 - rl, 0);
            m = __uint_as_float((u32)(150 + e - fb) << 23) * 1.5f;  // 1.5*2^(23+e-fb)
        }
        lut[tid] = m;
    }
}
__device__ __forceinline__ u32 pq_pos_raw(float x, const float* __restrict__ lut) {  // x >= 0
    u32 u = __float_as_uint(x);
    float c = lut[u >> 23];
    float q = (x + c) - c;
    q = fminf(fmaxf(q, 0x1p-12f), 0x1p12f);
    return u == 0u ? 0u : __float_as_uint(q);
}

// ---------- kernel 1 (R20: MERGED prep+prep2): all weight quantization in one launch ----------
__global__ __launch_bounds__(256) void prep_all_kernel(
    const float* __restrict__ w1, const float* __restrict__ w2,
    const float* __restrict__ fw2, const float* __restrict__ fw1,
    float* __restrict__ w1q, u16* __restrict__ w2frag, float* __restrict__ fc2wq,
    u16* __restrict__ fc1wqF) {
    int i = blockIdx.x * 256 + threadIdx.x;
    if (i < 288)  w1q[i]   = posit_q(w1[i]);
    if (i < 1280) fc2wq[i] = posit_q(fw2[i]);
    if (i < 18432) {
        int e = i & 7, lane = (i >> 3) & 63, c9 = i >> 9;
        int kc = c9 % 9, nt = c9 / 9;
        int n = nt * 16 + (lane & 15);
        int ci = ((lane >> 4) << 3) + e;
        w2frag[i] = f2b(posit_q(w2[n * 288 + ci * 9 + kc]));  // w2 flat [n][ci][kh][kw]
    }
    {   // fc1wqF[nt(8)][kk(288)][lane(64)][e(8)]: frag-linear fc1 weights (prep2 mapping)
        int e = i & 7, lane = (i >> 3) & 63, c = i >> 9;
        int kk = c % 288, nt = c / 288;
        int n = nt * 16 + (lane & 15);
        int k = kk * 32 + ((lane >> 4) << 3) + e;
        fc1wqF[i] = f2b(posit_q(fw1[(size_t)n * 9216 + k]));
    }
}

// ---------- kernel 2: fused pq(x) + conv1 + relu + pq + conv2(MFMA) + pool + bias + relu + pq ----------
// R18 TEXT — FROZEN (stable fingerprint: 137.5 us, VGPR 52, FETCH 9 MB, WRITE 77 MB, conflicts 2.26e7).
// R16 lesson: SQ_LDS_BANK_CONFLICT is invariant under intra-quarter-wave lane permutation -> the
// 5.5k conflict-cyc/block is the structural multi-beat cost of b128 at 2-lanes/bank, not fixable.
// R19 lesson: scalar fmaf only (pk_fma FTZ breaks denormal->minpos semantics, see posit_q note).
// Do NOT nt-hint the pooled stores: the 8 B u16-pair segments rely on L2 write-combining
// (WRITE_SIZE is a perfect 76.7 MB).
// NOTE: the phase-0 fc1wq write is LOAD-BEARING for the compiler's allocation — removing it in R12
// flipped scheduling into scratch-spill (VGPR 64, 600 MB HBM, 186 us). It targets a dummy region.
#define PLS 5416
__global__ __launch_bounds__(512, 4) void conv_fused_kernel(
    const float* __restrict__ x, const float* __restrict__ w1q, const float* __restrict__ b1,
    const u16* __restrict__ w2frag, const float* __restrict__ b2,
    const float* __restrict__ fw1, u16* __restrict__ fc1wq, u16* __restrict__ pooled) {
    __shared__ __align__(16) float sX[784];           // 3136 B
    __shared__ __align__(16) u16 sH1[4 * PLS];        // 43328 B
    __shared__ float sLut[256];                       // 1024 B (total ~47.5 KB)
    int img = blockIdx.x, tid = threadIdx.x;
    int wave = tid >> 6, lane = tid & 63;
    int col = lane & 15, quad = lane >> 4;

    lut_init(tid, sLut);

    // phase 0: pq input image -> LDS; also quantize this block's slice of fc1 weights (global)
    for (int i = tid; i < 784; i += 512) sX[i] = posit_q(x[(size_t)img * 784 + i]);
    if (tid < 288) fc1wq[(size_t)img * 288 + tid] = f2b(posit_q(fw1[(size_t)img * 288 + tid]));

    // conv1 weights for this thread's oc pair (registers)
    int ocp = tid & 15;
    float wreg[18];
#pragma unroll
    for (int j = 0; j < 18; ++j) wreg[j] = w1q[ocp * 18 + j];
    float bias0 = b1[ocp * 2], bias1 = b1[ocp * 2 + 1];

    __syncthreads();

    // phase 1: conv1 (+bias+relu+pq) -> sH1 planes, 2x2 patches. thread = (pgrp = tid>>4, ocp).
    int pgrp = tid >> 4;
    u16* h1dst = &sH1[(ocp >> 2) * PLS + 2 * (ocp & 3)];
    for (int it = 0; it < 6; ++it) {
        int q = it * 32 + pgrp;
        if (q < 169) {
            int py = q / 13, px = q - py * 13;
            const float* base = &sX[2 * py * 28 + 2 * px];
            float in4[4][4];
#pragma unroll
            for (int r = 0; r < 4; ++r) {
                float2 lo = *(const float2*)(base + r * 28);
                float2 hi = *(const float2*)(base + r * 28 + 2);
                in4[r][0] = lo.x; in4[r][1] = lo.y; in4[r][2] = hi.x; in4[r][3] = hi.y;
            }
#pragma unroll
            for (int dy = 0; dy < 2; ++dy)
#pragma unroll
            for (int dx = 0; dx < 2; ++dx) {
                float a0 = bias0, a1 = bias1;
#pragma unroll
                for (int j = 0; j < 9; ++j) {
                    float v = in4[dy + j / 3][dx + j % 3];
                    a0 = fmaf(wreg[j], v, a0);
                    a1 = fmaf(wreg[9 + j], v, a1);
                }
                u32 r0 = pq_pos_raw(fmaxf(a0, 0.f), sLut);
                u32 r1 = pq_pos_raw(fmaxf(a1, 0.f), sLut);
                int p = (2 * py + dy) * 26 + 2 * px + dx;
                *(u32*)&h1dst[p * 8] = (r0 >> 16) | (r1 & 0xFFFF0000u);
            }
        }
    }

    // conv2 B-frags for this wave's n-pair
    __syncthreads();
    int npair = wave & 1, mq = wave >> 1;
    bf16x8 bfrag[2][9];
#pragma unroll
    for (int j = 0; j < 2; ++j)
#pragma unroll
        for (int kc = 0; kc < 9; ++kc)
            bfrag[j][kc] = *(const bf16x8*)(w2frag + (((npair * 2 + j) * 9 + kc) * 64 + lane) * 8);
    float cb0 = b2[(npair * 2) * 16 + col];
    float cb1 = b2[(npair * 2 + 1) * 16 + col];
    // direct-global epilogue bases: pooled[img][c*144 + window], c = (npair*2+j)*16+col
    u16* gout0 = pooled + (size_t)img * 9216 + ((npair * 2) * 16 + col) * 144;
    u16* gout1 = pooled + (size_t)img * 9216 + ((npair * 2 + 1) * 16 + col) * 144;
    const u16* aplane = &sH1[quad * PLS];
    int wsl = col >> 2;
    int wswz = ((wsl & 1) << 1) | (wsl >> 1);    // bitswap2: 0,1,2,3 -> 0,2,1,3 (A-row window slot)
    int qswz = ((quad & 1) << 1) | (quad >> 1);  // lane's acc window slot (same bitswap on quad)
    int wi = col & 3;

    // phase 2: conv2 MFMA + pool(max) + bias + relu + pq. Wave: m-tiles mq*9..mq*9+8, 2 n-tiles.
    for (int t = 0; t < 9; ++t) {
        int mt = mq * 9 + t;
        int pp = mt * 4 + wswz;                 // swizzled pool-window assignment (A-row = lane&15)
        int py = pp / 12, px_ = pp - py * 12;
        int oh = 2 * py + (wi >> 1), ow = 2 * px_ + (wi & 1);
        const u16* ap = aplane + (oh * 26 + ow) * 8;
        f32x4 acc0 = {0.f, 0.f, 0.f, 0.f}, acc1 = {0.f, 0.f, 0.f, 0.f};
#pragma unroll
        for (int kc = 0; kc < 9; ++kc) {
            int kh = kc / 3, kw = kc - kh * 3;
            bf16x8 af = *(const bf16x8*)(ap + (kh * 26 + kw) * 8);
            acc0 = __builtin_amdgcn_mfma_f32_16x16x32_bf16(af, bfrag[0][kc], acc0, 0, 0, 0);
            acc1 = __builtin_amdgcn_mfma_f32_16x16x32_bf16(af, bfrag[1][kc], acc1, 0, 0, 0);
        }
        // C/D: row = quad*4+reg -> lane's 4 regs = window mt*4+qswz; max commutes exactly.
        float mx0 = fmaxf(fmaxf(acc0[0], acc0[1]), fmaxf(acc0[2], acc0[3]));
        float mx1 = fmaxf(fmaxf(acc1[0], acc1[1]), fmaxf(acc1[2], acc1[3]));
        gout0[mt * 4 + qswz] = (u16)(pq_pos_raw(fmaxf(mx0 + cb0, 0.f), sLut) >> 16);
        gout1[mt * 4 + qswz] = (u16)(pq_pos_raw(fmaxf(mx1 + cb1, 0.f), sLut) >> 16);
    }
}

// ---------- kernel 3a: fc1 partial GEMM — B-AMORTIZED + A-PREFETCH + NT-STREAMS v6 (R21) ----------
// R21 theory: fc1_part's B-loads (2.36 MB fc1wqF, read by every block) are being EVICTED from the
// per-XCD L2 by the zero-reuse A-stream (75.5 MB read-once) + part writes — R18's −8.3 us matched
// the L2-BW delta of halved B exactly, implying B re-fetches from L3/HBM dominate the kernel
// (~302 MB at L3 speed ≈ 30-50 us, closing the accounting gap: total 223 − conv 136 − small ≈ 70).
// Fix: __builtin_nontemporal_load on A (read-once => no-allocate in L2) and nontemporal_store on
// part (read once later; 8.4 MB from HBM in fc2_red ≈ 1.3 us) — B keeps normal caching and stays
// L2-resident. Values unchanged -> bit-exact. If total is flat, theory is dead -> merge fc1+fc2.
__global__ __launch_bounds__(512, 2) void fc1_part_kernel(const u16* __restrict__ pooled,
    const u16* __restrict__ fc1wqF, float* __restrict__ part) {
    __shared__ __align__(16) float sAcc[8448];         // 33792 B
    int blk = blockIdx.x, tid = threadIdx.x;
    int mbp = blk >> 2, ks = blk & 3;                  // mbp in 0..127 (pair of mb), ks in 0..3
    int wave = tid >> 6, lane = tid & 63;
    int row = lane & 15, quad = lane >> 4;

    const bf16x8* bbase = (const bf16x8*)fc1wqF + (size_t)(ks * 72 + wave * 9) * 64 + lane;
    const u16* abase0 = pooled + (size_t)(mbp * 32 + row) * 9216 + ks * 2304 + wave * 288 + quad * 8;
    const u16* abase1 = abase0 + (size_t)16 * 9216;
    f32x4 acc[2][8];
#pragma unroll
    for (int mi = 0; mi < 2; ++mi)
#pragma unroll
        for (int nt = 0; nt < 8; ++nt) acc[mi][nt] = f32x4{0.f, 0.f, 0.f, 0.f};
    bf16x8 a0n = __builtin_nontemporal_load((const bf16x8*)abase0);   // prefetch k2=0, nt (read-once)
    bf16x8 a1n = __builtin_nontemporal_load((const bf16x8*)abase1);
#pragma unroll 1
    for (int k2 = 0; k2 < 9; ++k2) {
        bf16x8 a0 = a0n, a1 = a1n;
        if (k2 < 8) {                                  // issue next A-loads early (HBM latency hide)
            a0n = __builtin_nontemporal_load((const bf16x8*)(abase0 + (k2 + 1) * 32));
            a1n = __builtin_nontemporal_load((const bf16x8*)(abase1 + (k2 + 1) * 32));
        }
#pragma unroll
        for (int nt = 0; nt < 8; ++nt) {
            bf16x8 b = bbase[((size_t)nt * 288 + k2) * 64];  // dense 1 KB wave-load, L2-cached
            acc[0][nt] = __builtin_amdgcn_mfma_f32_16x16x32_bf16(a0, b, acc[0][nt], 0, 0, 0);
            acc[1][nt] = __builtin_amdgcn_mfma_f32_16x16x32_bf16(a1, b, acc[1][nt], 0, 0, 0);
        }
    }
    // per-mb reduction, replayed twice with the EXACT old tree (bit-exact), sAcc reused between.
#pragma unroll
    for (int mi = 0; mi < 2; ++mi) {
        if (mi) __syncthreads();                       // writeout of pass 0 done before overwrite
        if (wave < 4) {
#pragma unroll
            for (int nt = 0; nt < 8; ++nt)
#pragma unroll
                for (int r = 0; r < 4; ++r)
                    sAcc[wave * 2112 + (quad * 4 + r) * 132 + nt * 16 + row] = acc[mi][nt][r];
        }
        __syncthreads();
        if (wave >= 4) {
#pragma unroll
            for (int nt = 0; nt < 8; ++nt)
#pragma unroll
                for (int r = 0; r < 4; ++r)
                    sAcc[(wave - 4) * 2112 + (quad * 4 + r) * 132 + nt * 16 + row] += acc[mi][nt][r];
        }
        __syncthreads();
        size_t pbase = ((size_t)((mbp * 2 + mi) * 4 + ks)) * 2048;
        for (int e = tid; e < 2048; e += 512) {
            int o = (e >> 7) * 132 + (e & 127);
            float v = sAcc[o] + sAcc[2112 + o] + sAcc[4224 + o] + sAcc[6336 + o];
            __builtin_nontemporal_store(v, &part[pbase + e]);   // read-once stream, keep out of L2
        }
    }
}

// ---------- kernel 3b: reduce K-partials + bias + relu + pq, fused fc2 ----------
__global__ __launch_bounds__(256) void fc2_red_kernel(const float* __restrict__ part,
    const float* __restrict__ fc1b, const float* __restrict__ fc2wq,
    const float* __restrict__ fc2b, float* __restrict__ out) {
    __shared__ __align__(16) u16 sFc1[2048];
    __shared__ float sW2[1280];
    __shared__ float sB2[16];
    __shared__ float sLut[256];
    int mb = blockIdx.x, tid = threadIdx.x;
    lut_init(tid, sLut);
    for (int i = tid; i < 1280; i += 256) sW2[i] = fc2wq[i];
    if (tid < 10) sB2[tid] = fc2b[tid];
    __syncthreads();
    const float* pb = part + (size_t)mb * 4 * 2048;
    for (int e = tid; e < 2048; e += 256) {
        float s = pb[e] + pb[2048 + e] + pb[4096 + e] + pb[6144 + e];
        sFc1[e] = (u16)(pq_pos_raw(fmaxf(s + fc1b[e & 127], 0.f), sLut) >> 16);
    }
    __syncthreads();
    if (tid < 160) {
        int il = tid / 10, oc = tid - il * 10;
        float s = sB2[oc];
        const u16* hp = &sFc1[il * 128];
        const float* wp = &sW2[oc * 128];
#pragma unroll
        for (int k = 0; k < 128; ++k) s = fmaf(b2f(hp[k]), wp[k], s);
        out[(size_t)(mb * 16 + il) * 10 + oc] = s;
    }
}

extern "C" void kernel_launch(void* const* d_in, const int* in_sizes, int n_in,
                              void* d_out, int out_size, void* d_ws, size_t ws_size,
                              hipStream_t stream) {
    const float* x    = (const float*)d_in[0];
    const float* w1   = (const float*)d_in[1];
    const float* b1   = (const float*)d_in[2];
    const float* w2   = (const float*)d_in[3];
    const float* b2   = (const float*)d_in[4];
    const float* fw1  = (const float*)d_in[5];
    const float* fb1  = (const float*)d_in[6];
    const float* fw2  = (const float*)d_in[7];
    const float* fb2  = (const float*)d_in[8];
    float* out = (float*)d_out;

    char* ws = (char*)d_ws;
    float* w1q     = (float*)(ws + 0);           // 1152 B
    float* fc2wq   = (float*)(ws + 1280);        // 5120 B
    u16*   w2frag  = (u16*)(ws + 6400);          // 36864 B
    u16*   fc1wqF  = (u16*)(ws + 43520);         // 2359296 B, frag-linear (read by fc1_part)
    u16*   fc1dmy  = (u16*)(ws + 2402816);       // 2359296 B, k-linear DUMMY (kept for conv_fused's
                                                 //            allocation-stable phase-0 write; unread)
    u16*   pooled  = (u16*)(ws + 4762112);       // 75497472 B, [img][c*144 + y*12 + x] bf16
    float* part    = (float*)(ws + 80259584);    // 8388608 B, [mb*4+ks][16*128] f32
    // total ~88.6 MB

    prep_all_kernel<<<4608, 256, 0, stream>>>(w1, w2, fw2, fw1, w1q, w2frag, fc2wq, fc1wqF);
    conv_fused_kernel<<<4096, 512, 0, stream>>>(x, w1q, b1, w2frag, b2, fw1, fc1dmy, pooled);
    fc1_part_kernel<<<512, 512, 0, stream>>>(pooled, fc1wqF, part);
    fc2_red_kernel<<<256, 256, 0, stream>>>(part, fb1, fc2wq, fb2, out);
}

// Round 10
// 221.199 us; speedup vs baseline: 1.0568x; 1.0568x over previous
//
#include <hip/hip_runtime.h>

using u16 = unsigned short;
using u32 = unsigned int;
typedef __attribute__((ext_vector_type(8))) short bf16x8;
typedef __attribute__((ext_vector_type(4))) float f32x4;

// ---------- posit(8,1) round-to-nearest (float core, verified bit-exact on HW) ----------
// PITFALL (R19): no packed f32 math (v_pk_fma_f32 FTZ breaks denormal->minpos). Scalar fmaf only.
// PITFALL (R21): no __builtin_nontemporal_* on pooled/part — pooled is L2/L3-warm from conv_fused
// (NT loads forfeit hits) and NT stores perturb cross-kernel L2 state (+11 us total). Reverted.
__device__ __forceinline__ float posit_q(float x) {
    float a = __builtin_fabsf(x);
    u32 u = __float_as_uint(a);
    int logx = (int)(u >> 23) - 127;
    logx = logx < -60 ? -60 : (logx > 60 ? 60 : logx);
    float frac = __uint_as_float((u & 0x007fffffu) | 0x3f800000u);  // [1,2)
    int k = logx >> 1;                            // floor(logx/2), es=1
    int rl = (k >= 0) ? (k + 2) : (1 - k);        // regime length
    int fb = 6 - rl; fb = fb < 0 ? 0 : fb;        // fraction bits, <=4
    float step = (float)(1 << fb);
    float q = rintf(frac * step) * __uint_as_float((u32)(127 + logx - fb) << 23);
    q = fminf(fmaxf(q, 0x1p-12f), 0x1p12f);
    return (a > 0.0f) ? copysignf(q, x) : 0.0f;
}

__device__ __forceinline__ float b2f(u16 v) { return __uint_as_float((u32)v << 16); }
__device__ __forceinline__ u16 f2b(float f) { return (u16)(__float_as_uint(f) >> 16); }  // exact for posit values

// ---------- Dekker-LUT posit quantizer (exact RNE onto the posit grid; verified R8) ----------
__device__ __forceinline__ void lut_init(int tid, float* lut) {
    if (tid < 256) {
        int e = tid - 127;
        float m = 0.f;
        if (e >= -12 && e <= 12) {
            int k = e >> 1;
            int rl = max(k + 2, 1 - k);
            int fb = max(6 - rl, 0);
            m = __uint_as_float((u32)(150 + e - fb) << 23) * 1.5f;  // 1.5*2^(23+e-fb)
        }
        lut[tid] = m;
    }
}
__device__ __forceinline__ u32 pq_pos_raw(float x, const float* __restrict__ lut) {  // x >= 0
    u32 u = __float_as_uint(x);
    float c = lut[u >> 23];
    float q = (x + c) - c;
    q = fminf(fmaxf(q, 0x1p-12f), 0x1p12f);
    return u == 0u ? 0u : __float_as_uint(q);
}

// ---------- kernel 1 (R22: back to SMALL prep): w1, w2frag, fc2 only — fc1wqF moved into
// conv_fused's phase-0 stabilizer write (4096 blocks x 288 threads = exactly 1179648 elements).
__global__ __launch_bounds__(256) void prep_kernel(
    const float* __restrict__ w1, const float* __restrict__ w2,
    const float* __restrict__ fw2,
    float* __restrict__ w1q, u16* __restrict__ w2frag, float* __restrict__ fc2wq) {
    int i = blockIdx.x * 256 + threadIdx.x;
    if (i < 288)  w1q[i]   = posit_q(w1[i]);
    if (i < 1280) fc2wq[i] = posit_q(fw2[i]);
    if (i < 18432) {
        int e = i & 7, lane = (i >> 3) & 63, c9 = i >> 9;
        int kc = c9 % 9, nt = c9 / 9;
        int n = nt * 16 + (lane & 15);
        int ci = ((lane >> 4) << 3) + e;
        w2frag[i] = f2b(posit_q(w2[n * 288 + ci * 9 + kc]));  // w2 flat [n][ci][kh][kw]
    }
}

// ---------- kernel 2: fused pq(x) + conv1 + relu + pq + conv2(MFMA) + pool + bias + relu + pq ----------
// R18 COMPUTE TEXT — FROZEN (fingerprint: VGPR 52, FETCH 9 MB, WRITE 77 MB, conflicts 2.259e7;
// dur 136-150 us depending on cross-round L2/machine state — fingerprint, not dur, is the check).
// R16 lesson: SQ_LDS_BANK_CONFLICT invariant under intra-quarter-wave lane permutation (structural).
// R19 lesson: scalar fmaf only. R21 lesson: no NT hints.
// R22: the phase-0 stabilizer write (LOAD-BEARING for allocation — R12: removing it => scratch
// spill, VGPR 64, 600 MB HBM) now does REAL work: quantizes this block's 288-element slice of the
// frag-linear fc1wqF (formerly prep2's whole 4608-block launch). Same shape: tid<288, 1 load,
// posit_q, 1 store — only the address arithmetic differs.
#define PLS 5416
__global__ __launch_bounds__(512, 4) void conv_fused_kernel(
    const float* __restrict__ x, const float* __restrict__ w1q, const float* __restrict__ b1,
    const u16* __restrict__ w2frag, const float* __restrict__ b2,
    const float* __restrict__ fw1, u16* __restrict__ fc1wq, u16* __restrict__ pooled) {
    __shared__ __align__(16) float sX[784];           // 3136 B
    __shared__ __align__(16) u16 sH1[4 * PLS];        // 43328 B
    __shared__ float sLut[256];                       // 1024 B (total ~47.5 KB)
    int img = blockIdx.x, tid = threadIdx.x;
    int wave = tid >> 6, lane = tid & 63;
    int col = lane & 15, quad = lane >> 4;

    lut_init(tid, sLut);

    // phase 0: pq input image -> LDS; quantize this block's frag-linear fc1 weight slice (global)
    for (int i = tid; i < 784; i += 512) sX[i] = posit_q(x[(size_t)img * 784 + i]);
    if (tid < 288) {
        int j = img * 288 + tid;                       // global frag-linear index
        int e = j & 7, ln = (j >> 3) & 63, c = j >> 9;
        int kk = c % 288, nt = c / 288;
        int n = nt * 16 + (ln & 15);
        int k = kk * 32 + ((ln >> 4) << 3) + e;
        fc1wq[j] = f2b(posit_q(fw1[(size_t)n * 9216 + k]));
    }

    // conv1 weights for this thread's oc pair (registers)
    int ocp = tid & 15;
    float wreg[18];
#pragma unroll
    for (int j = 0; j < 18; ++j) wreg[j] = w1q[ocp * 18 + j];
    float bias0 = b1[ocp * 2], bias1 = b1[ocp * 2 + 1];

    __syncthreads();

    // phase 1: conv1 (+bias+relu+pq) -> sH1 planes, 2x2 patches. thread = (pgrp = tid>>4, ocp).
    int pgrp = tid >> 4;
    u16* h1dst = &sH1[(ocp >> 2) * PLS + 2 * (ocp & 3)];
    for (int it = 0; it < 6; ++it) {
        int q = it * 32 + pgrp;
        if (q < 169) {
            int py = q / 13, px = q - py * 13;
            const float* base = &sX[2 * py * 28 + 2 * px];
            float in4[4][4];
#pragma unroll
            for (int r = 0; r < 4; ++r) {
                float2 lo = *(const float2*)(base + r * 28);
                float2 hi = *(const float2*)(base + r * 28 + 2);
                in4[r][0] = lo.x; in4[r][1] = lo.y; in4[r][2] = hi.x; in4[r][3] = hi.y;
            }
#pragma unroll
            for (int dy = 0; dy < 2; ++dy)
#pragma unroll
            for (int dx = 0; dx < 2; ++dx) {
                float a0 = bias0, a1 = bias1;
#pragma unroll
                for (int j = 0; j < 9; ++j) {
                    float v = in4[dy + j / 3][dx + j % 3];
                    a0 = fmaf(wreg[j], v, a0);
                    a1 = fmaf(wreg[9 + j], v, a1);
                }
                u32 r0 = pq_pos_raw(fmaxf(a0, 0.f), sLut);
                u32 r1 = pq_pos_raw(fmaxf(a1, 0.f), sLut);
                int p = (2 * py + dy) * 26 + 2 * px + dx;
                *(u32*)&h1dst[p * 8] = (r0 >> 16) | (r1 & 0xFFFF0000u);
            }
        }
    }

    // conv2 B-frags for this wave's n-pair
    __syncthreads();
    int npair = wave & 1, mq = wave >> 1;
    bf16x8 bfrag[2][9];
#pragma unroll
    for (int j = 0; j < 2; ++j)
#pragma unroll
        for (int kc = 0; kc < 9; ++kc)
            bfrag[j][kc] = *(const bf16x8*)(w2frag + (((npair * 2 + j) * 9 + kc) * 64 + lane) * 8);
    float cb0 = b2[(npair * 2) * 16 + col];
    float cb1 = b2[(npair * 2 + 1) * 16 + col];
    // direct-global epilogue bases: pooled[img][c*144 + window], c = (npair*2+j)*16+col
    u16* gout0 = pooled + (size_t)img * 9216 + ((npair * 2) * 16 + col) * 144;
    u16* gout1 = pooled + (size_t)img * 9216 + ((npair * 2 + 1) * 16 + col) * 144;
    const u16* aplane = &sH1[quad * PLS];
    int wsl = col >> 2;
    int wswz = ((wsl & 1) << 1) | (wsl >> 1);    // bitswap2: 0,1,2,3 -> 0,2,1,3 (A-row window slot)
    int qswz = ((quad & 1) << 1) | (quad >> 1);  // lane's acc window slot (same bitswap on quad)
    int wi = col & 3;

    // phase 2: conv2 MFMA + pool(max) + bias + relu + pq. Wave: m-tiles mq*9..mq*9+8, 2 n-tiles.
    for (int t = 0; t < 9; ++t) {
        int mt = mq * 9 + t;
        int pp = mt * 4 + wswz;                 // swizzled pool-window assignment (A-row = lane&15)
        int py = pp / 12, px_ = pp - py * 12;
        int oh = 2 * py + (wi >> 1), ow = 2 * px_ + (wi & 1);
        const u16* ap = aplane + (oh * 26 + ow) * 8;
        f32x4 acc0 = {0.f, 0.f, 0.f, 0.f}, acc1 = {0.f, 0.f, 0.f, 0.f};
#pragma unroll
        for (int kc = 0; kc < 9; ++kc) {
            int kh = kc / 3, kw = kc - kh * 3;
            bf16x8 af = *(const bf16x8*)(ap + (kh * 26 + kw) * 8);
            acc0 = __builtin_amdgcn_mfma_f32_16x16x32_bf16(af, bfrag[0][kc], acc0, 0, 0, 0);
            acc1 = __builtin_amdgcn_mfma_f32_16x16x32_bf16(af, bfrag[1][kc], acc1, 0, 0, 0);
        }
        // C/D: row = quad*4+reg -> lane's 4 regs = window mt*4+qswz; max commutes exactly.
        float mx0 = fmaxf(fmaxf(acc0[0], acc0[1]), fmaxf(acc0[2], acc0[3]));
        float mx1 = fmaxf(fmaxf(acc1[0], acc1[1]), fmaxf(acc1[2], acc1[3]));
        gout0[mt * 4 + qswz] = (u16)(pq_pos_raw(fmaxf(mx0 + cb0, 0.f), sLut) >> 16);
        gout1[mt * 4 + qswz] = (u16)(pq_pos_raw(fmaxf(mx1 + cb1, 0.f), sLut) >> 16);
    }
}

// ---------- kernel 3a: fc1 partial GEMM — B-AMORTIZED + A-PREFETCH v5 (R20 TEXT, NT reverted) ----------
// R18: two mb's per block share each B wave-load (B traffic 604->302 MB; B is L2-resident —
// R18's −8.3 us matches 302 MB at 34.5 TB/s L2 speed). R20: 1-deep A-prefetch. R21's NT hints
// REVERTED (regressed +11 us: pooled is cache-warm, NT forfeits hits).
__global__ __launch_bounds__(512, 2) void fc1_part_kernel(const u16* __restrict__ pooled,
    const u16* __restrict__ fc1wqF, float* __restrict__ part) {
    __shared__ __align__(16) float sAcc[8448];         // 33792 B
    int blk = blockIdx.x, tid = threadIdx.x;
    int mbp = blk >> 2, ks = blk & 3;                  // mbp in 0..127 (pair of mb), ks in 0..3
    int wave = tid >> 6, lane = tid & 63;
    int row = lane & 15, quad = lane >> 4;

    const bf16x8* bbase = (const bf16x8*)fc1wqF + (size_t)(ks * 72 + wave * 9) * 64 + lane;
    const u16* abase0 = pooled + (size_t)(mbp * 32 + row) * 9216 + ks * 2304 + wave * 288 + quad * 8;
    const u16* abase1 = abase0 + (size_t)16 * 9216;
    f32x4 acc[2][8];
#pragma unroll
    for (int mi = 0; mi < 2; ++mi)
#pragma unroll
        for (int nt = 0; nt < 8; ++nt) acc[mi][nt] = f32x4{0.f, 0.f, 0.f, 0.f};
    bf16x8 a0n = *(const bf16x8*)(abase0);             // prefetch k2=0
    bf16x8 a1n = *(const bf16x8*)(abase1);
#pragma unroll 1
    for (int k2 = 0; k2 < 9; ++k2) {
        bf16x8 a0 = a0n, a1 = a1n;
        if (k2 < 8) {                                  // issue next A-loads early (HBM latency hide)
            a0n = *(const bf16x8*)(abase0 + (k2 + 1) * 32);
            a1n = *(const bf16x8*)(abase1 + (k2 + 1) * 32);
        }
#pragma unroll
        for (int nt = 0; nt < 8; ++nt) {
            bf16x8 b = bbase[((size_t)nt * 288 + k2) * 64];  // dense 1 KB wave-load, used TWICE
            acc[0][nt] = __builtin_amdgcn_mfma_f32_16x16x32_bf16(a0, b, acc[0][nt], 0, 0, 0);
            acc[1][nt] = __builtin_amdgcn_mfma_f32_16x16x32_bf16(a1, b, acc[1][nt], 0, 0, 0);
        }
    }
    // per-mb reduction, replayed twice with the EXACT old tree (bit-exact), sAcc reused between.
#pragma unroll
    for (int mi = 0; mi < 2; ++mi) {
        if (mi) __syncthreads();                       // writeout of pass 0 done before overwrite
        if (wave < 4) {
#pragma unroll
            for (int nt = 0; nt < 8; ++nt)
#pragma unroll
                for (int r = 0; r < 4; ++r)
                    sAcc[wave * 2112 + (quad * 4 + r) * 132 + nt * 16 + row] = acc[mi][nt][r];
        }
        __syncthreads();
        if (wave >= 4) {
#pragma unroll
            for (int nt = 0; nt < 8; ++nt)
#pragma unroll
                for (int r = 0; r < 4; ++r)
                    sAcc[(wave - 4) * 2112 + (quad * 4 + r) * 132 + nt * 16 + row] += acc[mi][nt][r];
        }
        __syncthreads();
        size_t pbase = ((size_t)((mbp * 2 + mi) * 4 + ks)) * 2048;
        for (int e = tid; e < 2048; e += 512) {
            int o = (e >> 7) * 132 + (e & 127);
            part[pbase + e] = sAcc[o] + sAcc[2112 + o] + sAcc[4224 + o] + sAcc[6336 + o];
        }
    }
}

// ---------- kernel 3b: reduce K-partials + bias + relu + pq, fused fc2 ----------
__global__ __launch_bounds__(256) void fc2_red_kernel(const float* __restrict__ part,
    const float* __restrict__ fc1b, const float* __restrict__ fc2wq,
    const float* __restrict__ fc2b, float* __restrict__ out) {
    __shared__ __align__(16) u16 sFc1[2048];
    __shared__ float sW2[1280];
    __shared__ float sB2[16];
    __shared__ float sLut[256];
    int mb = blockIdx.x, tid = threadIdx.x;
    lut_init(tid, sLut);
    for (int i = tid; i < 1280; i += 256) sW2[i] = fc2wq[i];
    if (tid < 10) sB2[tid] = fc2b[tid];
    __syncthreads();
    const float* pb = part + (size_t)mb * 4 * 2048;
    for (int e = tid; e < 2048; e += 256) {
        float s = pb[e] + pb[2048 + e] + pb[4096 + e] + pb[6144 + e];
        sFc1[e] = (u16)(pq_pos_raw(fmaxf(s + fc1b[e & 127], 0.f), sLut) >> 16);
    }
    __syncthreads();
    if (tid < 160) {
        int il = tid / 10, oc = tid - il * 10;
        float s = sB2[oc];
        const u16* hp = &sFc1[il * 128];
        const float* wp = &sW2[oc * 128];
#pragma unroll
        for (int k = 0; k < 128; ++k) s = fmaf(b2f(hp[k]), wp[k], s);
        out[(size_t)(mb * 16 + il) * 10 + oc] = s;
    }
}

extern "C" void kernel_launch(void* const* d_in, const int* in_sizes, int n_in,
                              void* d_out, int out_size, void* d_ws, size_t ws_size,
                              hipStream_t stream) {
    const float* x    = (const float*)d_in[0];
    const float* w1   = (const float*)d_in[1];
    const float* b1   = (const float*)d_in[2];
    const float* w2   = (const float*)d_in[3];
    const float* b2   = (const float*)d_in[4];
    const float* fw1  = (const float*)d_in[5];
    const float* fb1  = (const float*)d_in[6];
    const float* fw2  = (const float*)d_in[7];
    const float* fb2  = (const float*)d_in[8];
    float* out = (float*)d_out;

    char* ws = (char*)d_ws;
    float* w1q     = (float*)(ws + 0);           // 1152 B
    float* fc2wq   = (float*)(ws + 1280);        // 5120 B
    u16*   w2frag  = (u16*)(ws + 6400);          // 36864 B
    u16*   fc1wqF  = (u16*)(ws + 43520);         // 2359296 B, frag-linear (written by conv_fused
                                                 //            phase-0 stabilizer, read by fc1_part)
    u16*   pooled  = (u16*)(ws + 4762112);       // 75497472 B, [img][c*144 + y*12 + x] bf16
    float* part    = (float*)(ws + 80259584);    // 8388608 B, [mb*4+ks][16*128] f32
    // total ~88.6 MB

    prep_kernel<<<72, 256, 0, stream>>>(w1, w2, fw2, w1q, w2frag, fc2wq);
    conv_fused_kernel<<<4096, 512, 0, stream>>>(x, w1q, b1, w2frag, b2, fw1, fc1wqF, pooled);
    fc1_part_kernel<<<512, 512, 0, stream>>>(pooled, fc1wqF, part);
    fc2_red_kernel<<<256, 256, 0, stream>>>(part, fb1, fc2wq, fb2, out);
}